// Round 13
// baseline (646.132 us; speedup 1.0000x reference)
//
#include <hip/hip_runtime.h>
#include <cstdint>

#define TSIZE (1u << 19)
#define MASKU (TSIZE - 1u)
#define P1U 2654435761u

// clang native vector types for nontemporal builtins (HIP_vector_type is a
// class -- __builtin_nontemporal_* rejects it; r12 compile failure)
typedef float f32x2 __attribute__((ext_vector_type(2)));
typedef float f32x4 __attribute__((ext_vector_type(4)));

__device__ __forceinline__ float2 nt_load2(const float2* p) {
  f32x2 v = __builtin_nontemporal_load(reinterpret_cast<const f32x2*>(p));
  return make_float2(v.x, v.y);
}
__device__ __forceinline__ float4 nt_load4(const float4* p) {
  f32x4 v = __builtin_nontemporal_load(reinterpret_cast<const f32x4*>(p));
  return make_float4(v.x, v.y, v.z, v.w);
}
__device__ __forceinline__ void nt_store4(float4* p, float4 v) {
  f32x4 w; w.x = v.x; w.y = v.y; w.z = v.z; w.w = v.w;
  __builtin_nontemporal_store(w, reinterpret_cast<f32x4*>(p));
}

// hierarchical capacity bins:
//  - counters/slots at 16-px granularity (128x128 = 16384 children, mean 128)
//  - children of each 32-px parent contiguous: parent block = 4*144 = 576
//    slots = 9 waves, wave-aligned -> every wave within one 32-px parent
//  - records AoS float4 (r11 A/B: beats SoA by ~90us in main kernel)
//  - NT stores/loads: kill L2 line-bounce on scatter + out-stream pollution
#define CBINS_X 128
#define NCB (CBINS_X * CBINS_X)     // 16384 child bins
#define CAP 144                     // mean 128 + 1.4 sigma; ~6.5K ovf expected
#define SLOTS (NCB * CAP)           // 2,359,296 -> 9216 blocks of 256

// ---------------- embed core (numerics FROZEN since round 2) ----------------
// RES[15] = 2047 (verified round 2). Levels 0-11 direct (fused 16B pair
// gathers); 12-15 hash; reference searchsorted == identity lookup.
// MLP structure: all 40 gathers issued before any lerp. Out stores NT.
__device__ __forceinline__ void embed_point(float2 xv, int orig,
                                            const float* __restrict__ tables,
                                            float* __restrict__ out) {
  constexpr int RESV[16] = {16, 22, 30, 42, 58, 80, 111, 153,
                            212, 294, 406, 561, 776, 1072, 1482, 2047};
  const float2* tabs = reinterpret_cast<const float2*>(tables);

  float4 lo[12], hi[12];
  float2 eh[4][4];
  float w0a[16], w1a[16];

#pragma unroll
  for (int l = 0; l < 12; ++l) {
    const int res = RESV[l];
    const float gs = (float)(2048.0 / (double)res);  // f32(double(2048/res))
    float f0 = floorf(xv.x / gs);
    float f1 = floorf(xv.y / gs);
    float g0 = f0 * gs;
    float g1 = f1 * gs;
    w0a[l] = (xv.x - g0) / ((g0 + gs) - g0);
    w1a[l] = (xv.y - g1) / ((g1 + gs) - g1);
    int base = (int)f0 * res + (int)f1;
    const float2* tab = tabs + (size_t)l * TSIZE;
    lo[l] = *reinterpret_cast<const float4*>(tab + base);
    hi[l] = *reinterpret_cast<const float4*>(tab + base + res);
  }
#pragma unroll
  for (int l = 0; l < 4; ++l) {
    const int res = RESV[12 + l];
    const float gs = (float)(2048.0 / (double)res);
    float f0 = floorf(xv.x / gs);
    float f1 = floorf(xv.y / gs);
    float g0 = f0 * gs;
    float g1 = f1 * gs;
    w0a[12 + l] = (xv.x - g0) / ((g0 + gs) - g0);
    w1a[12 + l] = (xv.y - g1) / ((g1 + gs) - g1);
    uint32_t u0 = (uint32_t)(int)f0;
    uint32_t u1m = (uint32_t)(int)f1 * P1U;
    const float2* tab = tabs + (size_t)(12 + l) * TSIZE;
    eh[l][0] = tab[(u0 ^ u1m) & MASKU];
    eh[l][1] = tab[(u0 ^ (u1m + P1U)) & MASKU];
    eh[l][2] = tab[((u0 + 1u) ^ u1m) & MASKU];
    eh[l][3] = tab[((u0 + 1u) ^ (u1m + P1U)) & MASKU];
  }

  float feat[32];
#pragma unroll
  for (int l = 0; l < 12; ++l) {
    float w0 = w0a[l], w1 = w1a[l];
    float omw0 = 1.0f - w0, omw1 = 1.0f - w1;
    float c0x = lo[l].x * omw1 + lo[l].z * w1;
    float c0y = lo[l].y * omw1 + lo[l].w * w1;
    float c1x = hi[l].x * omw1 + hi[l].z * w1;
    float c1y = hi[l].y * omw1 + hi[l].w * w1;
    feat[2 * l]     = c0x * omw0 + c1x * w0;
    feat[2 * l + 1] = c0y * omw0 + c1y * w0;
  }
#pragma unroll
  for (int l = 0; l < 4; ++l) {
    float w0 = w0a[12 + l], w1 = w1a[12 + l];
    float omw0 = 1.0f - w0, omw1 = 1.0f - w1;
    float c0x = eh[l][0].x * omw1 + eh[l][1].x * w1;
    float c0y = eh[l][0].y * omw1 + eh[l][1].y * w1;
    float c1x = eh[l][2].x * omw1 + eh[l][3].x * w1;
    float c1y = eh[l][2].y * omw1 + eh[l][3].y * w1;
    feat[24 + 2 * l]     = c0x * omw0 + c1x * w0;
    feat[24 + 2 * l + 1] = c0y * omw0 + c1y * w0;
  }

  float4* o = reinterpret_cast<float4*>(out) + (size_t)orig * 8;
#pragma unroll
  for (int j = 0; j < 8; ++j) {
    nt_store4(o + j,
              make_float4(feat[4 * j], feat[4 * j + 1], feat[4 * j + 2], feat[4 * j + 3]));
  }
}

// ---------------- hierarchical capacity-bin sort (AoS float4, NT) -----------

// child index: 4 children of each 32-px parent are contiguous
__device__ __forceinline__ int child_of(float2 xv) {
  int bx = min((int)(xv.x * 0.0625f), CBINS_X - 1);   // 16-px coords
  int by = min((int)(xv.y * 0.0625f), CBINS_X - 1);
  int parent = ((bx >> 1) << 6) + (by >> 1);          // 64x64 parents
  int quad = ((bx & 1) << 1) + (by & 1);
  return (parent << 2) + quad;
}

__global__ __launch_bounds__(256) void scatter_cap(
    const float2* __restrict__ xs, int* __restrict__ cnt,
    float4* __restrict__ recs,
    int* __restrict__ ovf, int* __restrict__ ovf_cnt, int B) {
  int p = blockIdx.x * 256 + threadIdx.x;
  if (p >= B) return;
  float2 xv = nt_load2(xs + p);                     // streaming read-once
  int child = child_of(xv);
  int pos = atomicAdd(&cnt[child], 1);
  if (pos < CAP) {
    nt_store4(recs + child * CAP + pos,
              make_float4(xv.x, xv.y, __int_as_float(p), 0.0f));  // no bounce
  } else {
    int o = atomicAdd(ovf_cnt, 1);
    __builtin_nontemporal_store(p, ovf + o);        // ovf capacity == B
  }
}

__global__ __launch_bounds__(256, 2) void hashenc_cap(
    const float4* __restrict__ recs, const int* __restrict__ cnt,
    const float* __restrict__ tables, float* __restrict__ out) {
  int bid = blockIdx.x;
  int nb = gridDim.x;  // 9216, divisible by 8
  int chunk = nb >> 3;
  bid = (bid & 7) * chunk + (bid >> 3);   // XCD slab swizzle (bijective)
  int slot = bid * 256 + threadIdx.x;
  int child = slot / CAP;                 // const divisor -> magic mul
  int pos = slot - child * CAP;
  int c = cnt[child];
  if (pos >= min(c, CAP)) return;
  float4 r = nt_load4(recs + slot);       // read-once stream
  embed_point(make_float2(r.x, r.y), __float_as_int(r.z), tables, out);
}

__global__ __launch_bounds__(256) void ovf_kernel(
    const float2* __restrict__ xs, const int* __restrict__ ovf,
    const int* __restrict__ ovf_cnt, const float* __restrict__ tables,
    float* __restrict__ out) {
  int n = *ovf_cnt;
  for (int i = blockIdx.x * 256 + threadIdx.x; i < n; i += gridDim.x * 256) {
    int p = ovf[i];
    embed_point(xs[p], p, tables, out);
  }
}

// ---------------- unsorted fallback -----------------------------------------

__global__ __launch_bounds__(256, 2) void hashenc_plain(
    const float2* __restrict__ xs, const float* __restrict__ tables,
    float* __restrict__ out, int B) {
  int p = blockIdx.x * 256 + threadIdx.x;
  if (p >= B) return;
  embed_point(xs[p], p, tables, out);
}

// ---------------- launch ----------------------------------------------------

extern "C" void kernel_launch(void* const* d_in, const int* in_sizes, int n_in,
                              void* d_out, int out_size, void* d_ws, size_t ws_size,
                              hipStream_t stream) {
  const float2* xs = (const float2*)d_in[0];
  const float* tables = (const float*)d_in[1];
  float* out = (float*)d_out;
  int B = in_sizes[0] / 2;
  int blocks = (B + 255) / 256;
  char* ws = (char*)d_ws;

  // layout: recs (16B*SLOTS) | ovf (4B*B) | cnt (4B*NCB) | ovf_cnt (+pad)
  size_t c_recs = 0;
  size_t c_ovf = c_recs + (size_t)SLOTS * 16;
  size_t c_cnt = c_ovf + (size_t)B * 4;
  size_t c_ocnt = c_cnt + (size_t)NCB * 4;
  size_t need = c_ocnt + 64;

  bool grid_ok = (blocks & 7) == 0;
  if (grid_ok && ws_size >= need) {
    float4* recs = (float4*)(ws + c_recs);
    int* ovf = (int*)(ws + c_ovf);
    int* cnt = (int*)(ws + c_cnt);
    int* ovf_cnt = (int*)(ws + c_ocnt);
    (void)hipMemsetAsync(cnt, 0, (size_t)NCB * 4 + 64, stream);  // cnt+ovf_cnt
    hipLaunchKernelGGL(scatter_cap, dim3(blocks), dim3(256), 0, stream,
                       xs, cnt, recs, ovf, ovf_cnt, B);
    hipLaunchKernelGGL(hashenc_cap, dim3(SLOTS / 256), dim3(256), 0, stream,
                       recs, cnt, tables, out);
    hipLaunchKernelGGL(ovf_kernel, dim3(32), dim3(256), 0, stream,
                       xs, ovf, ovf_cnt, tables, out);
  } else {
    hipLaunchKernelGGL(hashenc_plain, dim3(blocks), dim3(256), 0, stream,
                       xs, tables, out, B);
  }
}

// Round 14
// 401.759 us; speedup vs baseline: 1.6083x; 1.6083x over previous
//
#include <hip/hip_runtime.h>
#include <cstdint>

#define TSIZE (1u << 19)
#define MASKU (TSIZE - 1u)
#define P1U 2654435761u

// Quadrant-chunked hierarchical capacity bins.
//  - image split into 4 quadrants (1024x1024 px); per quadrant: scatter that
//    quadrant's points into a 9.4MB record buffer (L2-resident -> no partial
//    line RMW amplification; r11 showed 47MB region = 3.5x write amp), then
//    embed, reusing the buffer for the next quadrant.
//  - within a quadrant: 64x64 children (16px), 4 children of each 32-px
//    parent contiguous -> parent block = 4*144 = 576 slots = 9 waves.
//  - records AoS float4 (r11 A/B: beats SoA by ~90us in main kernel).
//  - NO nontemporal anywhere (r13: NT bypasses L2 write-combining, 3.3x amp).
#define QBINS_X 64
#define NCBQ (QBINS_X * QBINS_X)    // 4096 children per quadrant
#define CAP 144                     // mean 128 + 1.4 sigma
#define SLOTS_Q (NCBQ * CAP)        // 589,824 -> 2304 blocks of 256

// ---------------- embed core (numerics FROZEN since round 2) ----------------
// RES[15] = 2047 (verified round 2). Levels 0-11 direct (fused 16B pair
// gathers); 12-15 hash; reference searchsorted == identity lookup.
// MLP structure: all 40 gathers issued before any lerp.
__device__ __forceinline__ void embed_point(float2 xv, int orig,
                                            const float* __restrict__ tables,
                                            float* __restrict__ out) {
  constexpr int RESV[16] = {16, 22, 30, 42, 58, 80, 111, 153,
                            212, 294, 406, 561, 776, 1072, 1482, 2047};
  const float2* tabs = reinterpret_cast<const float2*>(tables);

  float4 lo[12], hi[12];
  float2 eh[4][4];
  float w0a[16], w1a[16];

#pragma unroll
  for (int l = 0; l < 12; ++l) {
    const int res = RESV[l];
    const float gs = (float)(2048.0 / (double)res);  // f32(double(2048/res))
    float f0 = floorf(xv.x / gs);
    float f1 = floorf(xv.y / gs);
    float g0 = f0 * gs;
    float g1 = f1 * gs;
    w0a[l] = (xv.x - g0) / ((g0 + gs) - g0);
    w1a[l] = (xv.y - g1) / ((g1 + gs) - g1);
    int base = (int)f0 * res + (int)f1;
    const float2* tab = tabs + (size_t)l * TSIZE;
    lo[l] = *reinterpret_cast<const float4*>(tab + base);
    hi[l] = *reinterpret_cast<const float4*>(tab + base + res);
  }
#pragma unroll
  for (int l = 0; l < 4; ++l) {
    const int res = RESV[12 + l];
    const float gs = (float)(2048.0 / (double)res);
    float f0 = floorf(xv.x / gs);
    float f1 = floorf(xv.y / gs);
    float g0 = f0 * gs;
    float g1 = f1 * gs;
    w0a[12 + l] = (xv.x - g0) / ((g0 + gs) - g0);
    w1a[12 + l] = (xv.y - g1) / ((g1 + gs) - g1);
    uint32_t u0 = (uint32_t)(int)f0;
    uint32_t u1m = (uint32_t)(int)f1 * P1U;
    const float2* tab = tabs + (size_t)(12 + l) * TSIZE;
    eh[l][0] = tab[(u0 ^ u1m) & MASKU];
    eh[l][1] = tab[(u0 ^ (u1m + P1U)) & MASKU];
    eh[l][2] = tab[((u0 + 1u) ^ u1m) & MASKU];
    eh[l][3] = tab[((u0 + 1u) ^ (u1m + P1U)) & MASKU];
  }

  float feat[32];
#pragma unroll
  for (int l = 0; l < 12; ++l) {
    float w0 = w0a[l], w1 = w1a[l];
    float omw0 = 1.0f - w0, omw1 = 1.0f - w1;
    float c0x = lo[l].x * omw1 + lo[l].z * w1;
    float c0y = lo[l].y * omw1 + lo[l].w * w1;
    float c1x = hi[l].x * omw1 + hi[l].z * w1;
    float c1y = hi[l].y * omw1 + hi[l].w * w1;
    feat[2 * l]     = c0x * omw0 + c1x * w0;
    feat[2 * l + 1] = c0y * omw0 + c1y * w0;
  }
#pragma unroll
  for (int l = 0; l < 4; ++l) {
    float w0 = w0a[12 + l], w1 = w1a[12 + l];
    float omw0 = 1.0f - w0, omw1 = 1.0f - w1;
    float c0x = eh[l][0].x * omw1 + eh[l][1].x * w1;
    float c0y = eh[l][0].y * omw1 + eh[l][1].y * w1;
    float c1x = eh[l][2].x * omw1 + eh[l][3].x * w1;
    float c1y = eh[l][2].y * omw1 + eh[l][3].y * w1;
    feat[24 + 2 * l]     = c0x * omw0 + c1x * w0;
    feat[24 + 2 * l + 1] = c0y * omw0 + c1y * w0;
  }

  float4* o = reinterpret_cast<float4*>(out) + (size_t)orig * 8;
#pragma unroll
  for (int j = 0; j < 8; ++j) {
    o[j] = make_float4(feat[4 * j], feat[4 * j + 1], feat[4 * j + 2], feat[4 * j + 3]);
  }
}

// ---------------- quadrant-chunked capacity-bin sort ------------------------

// global 16-px bin coords; quadrant = which 64x64-child block
__device__ __forceinline__ void bin_coords(float2 xv, int& gbx, int& gby) {
  gbx = min((int)(xv.x * 0.0625f), 127);
  gby = min((int)(xv.y * 0.0625f), 127);
}

// child index within quadrant: 4 children of each 32-px parent contiguous
__device__ __forceinline__ int child_local(int gbx, int gby) {
  int lbx = gbx & 63, lby = gby & 63;
  int parent = ((lbx >> 1) << 5) + (lby >> 1);   // 32x32 parents
  int quad = ((lbx & 1) << 1) + (lby & 1);
  return (parent << 2) + quad;
}

__global__ __launch_bounds__(256) void scatter_q(
    const float2* __restrict__ xs, int* __restrict__ cnt_q,
    float4* __restrict__ recs,
    int* __restrict__ ovf, int* __restrict__ ovf_cnt, int B, int q) {
  int p = blockIdx.x * 256 + threadIdx.x;
  if (p >= B) return;
  float2 xv = xs[p];
  int gbx, gby;
  bin_coords(xv, gbx, gby);
  if (((gbx >> 6) * 2 + (gby >> 6)) != q) return;   // not this quadrant
  int child = child_local(gbx, gby);
  int pos = atomicAdd(&cnt_q[child], 1);
  if (pos < CAP) {
    recs[child * CAP + pos] = make_float4(xv.x, xv.y, __int_as_float(p), 0.0f);
  } else {
    int o = atomicAdd(ovf_cnt, 1);
    ovf[o] = p;  // ovf capacity == B: can never overflow
  }
}

__global__ __launch_bounds__(256, 2) void hashenc_q(
    const float4* __restrict__ recs, const int* __restrict__ cnt_q,
    const float* __restrict__ tables, float* __restrict__ out) {
  int bid = blockIdx.x;
  int nb = gridDim.x;  // 2304, divisible by 8
  int chunk = nb >> 3;
  bid = (bid & 7) * chunk + (bid >> 3);   // XCD slab swizzle (bijective)
  int slot = bid * 256 + threadIdx.x;
  int child = slot / CAP;                 // const divisor -> magic mul
  int pos = slot - child * CAP;
  int c = cnt_q[child];
  if (pos >= min(c, CAP)) return;
  float4 r = recs[slot];                  // slot-coalesced 16B read (L2-hot)
  embed_point(make_float2(r.x, r.y), __float_as_int(r.z), tables, out);
}

__global__ __launch_bounds__(256) void ovf_kernel(
    const float2* __restrict__ xs, const int* __restrict__ ovf,
    const int* __restrict__ ovf_cnt, const float* __restrict__ tables,
    float* __restrict__ out) {
  int n = *ovf_cnt;
  for (int i = blockIdx.x * 256 + threadIdx.x; i < n; i += gridDim.x * 256) {
    int p = ovf[i];
    embed_point(xs[p], p, tables, out);
  }
}

// ---------------- unsorted fallback -----------------------------------------

__global__ __launch_bounds__(256, 2) void hashenc_plain(
    const float2* __restrict__ xs, const float* __restrict__ tables,
    float* __restrict__ out, int B) {
  int p = blockIdx.x * 256 + threadIdx.x;
  if (p >= B) return;
  embed_point(xs[p], p, tables, out);
}

// ---------------- launch ----------------------------------------------------

extern "C" void kernel_launch(void* const* d_in, const int* in_sizes, int n_in,
                              void* d_out, int out_size, void* d_ws, size_t ws_size,
                              hipStream_t stream) {
  const float2* xs = (const float2*)d_in[0];
  const float* tables = (const float*)d_in[1];
  float* out = (float*)d_out;
  int B = in_sizes[0] / 2;
  int blocks = (B + 255) / 256;
  char* ws = (char*)d_ws;

  // layout: recs (16B*SLOTS_Q, reused per quadrant) | ovf (4B*B) |
  //         cnt (4 quadrants x NCBQ x 4B) | ovf_cnt (+pad)
  size_t c_recs = 0;
  size_t c_ovf = c_recs + (size_t)SLOTS_Q * 16;
  size_t c_cnt = c_ovf + (size_t)B * 4;
  size_t c_ocnt = c_cnt + (size_t)4 * NCBQ * 4;
  size_t need = c_ocnt + 64;

  bool grid_ok = (blocks & 7) == 0;
  if (grid_ok && ws_size >= need) {
    float4* recs = (float4*)(ws + c_recs);
    int* ovf = (int*)(ws + c_ovf);
    int* cnt = (int*)(ws + c_cnt);
    int* ovf_cnt = (int*)(ws + c_ocnt);
    // zero all 4 quadrant cnt arrays + ovf_cnt in one memset (contiguous)
    (void)hipMemsetAsync(cnt, 0, (size_t)4 * NCBQ * 4 + 64, stream);
    for (int q = 0; q < 4; ++q) {
      int* cnt_q = cnt + q * NCBQ;
      hipLaunchKernelGGL(scatter_q, dim3(blocks), dim3(256), 0, stream,
                         xs, cnt_q, recs, ovf, ovf_cnt, B, q);
      hipLaunchKernelGGL(hashenc_q, dim3(SLOTS_Q / 256), dim3(256), 0, stream,
                         recs, cnt_q, tables, out);
    }
    hipLaunchKernelGGL(ovf_kernel, dim3(32), dim3(256), 0, stream,
                       xs, ovf, ovf_cnt, tables, out);
  } else {
    hipLaunchKernelGGL(hashenc_plain, dim3(blocks), dim3(256), 0, stream,
                       xs, tables, out, B);
  }
}

// Round 15
// 306.031 us; speedup vs baseline: 2.1113x; 1.3128x over previous
//
#include <hip/hip_runtime.h>
#include <cstdint>

#define TSIZE (1u << 19)
#define MASKU (TSIZE - 1u)
#define P1U 2654435761u

// Per-XCD partitioned capacity bins (r15).
//  - 128x128 children (16px, hierarchical: 4 children of a 32-px parent
//    contiguous). Each block writes ONLY partition blockIdx&7 (its XCD under
//    the round-robin mapping) -> every record/counter line is written by one
//    XCD only -> no cross-XCD dirty-line bounce (r11: WRITE 133MB = 3.5x amp;
//    r14 showed it is not an L2-capacity effect).
//  - per (xcd,child): mean 16 pts, CAPX=32 (+4.3 sigma, pow2 indexing).
//  - records AoS float4 (r11 A/B); NO nontemporal (r13); ws = 1 GiB (r14).
#define CBINS_X 128
#define NCHILD (CBINS_X * CBINS_X)      // 16384 children
#define XPART 8
#define CAPX 32
#define SLOTS (XPART * NCHILD * CAPX)   // 4,194,304 -> 16384 blocks of 256

// ---------------- embed core (numerics FROZEN since round 2) ----------------
// RES[15] = 2047 (verified round 2). Levels 0-11 direct (fused 16B pair
// gathers); 12-15 hash; reference searchsorted == identity lookup.
// MLP structure: all 40 gathers issued before any lerp.
__device__ __forceinline__ void embed_point(float2 xv, int orig,
                                            const float* __restrict__ tables,
                                            float* __restrict__ out) {
  constexpr int RESV[16] = {16, 22, 30, 42, 58, 80, 111, 153,
                            212, 294, 406, 561, 776, 1072, 1482, 2047};
  const float2* tabs = reinterpret_cast<const float2*>(tables);

  float4 lo[12], hi[12];
  float2 eh[4][4];
  float w0a[16], w1a[16];

#pragma unroll
  for (int l = 0; l < 12; ++l) {
    const int res = RESV[l];
    const float gs = (float)(2048.0 / (double)res);  // f32(double(2048/res))
    float f0 = floorf(xv.x / gs);
    float f1 = floorf(xv.y / gs);
    float g0 = f0 * gs;
    float g1 = f1 * gs;
    w0a[l] = (xv.x - g0) / ((g0 + gs) - g0);
    w1a[l] = (xv.y - g1) / ((g1 + gs) - g1);
    int base = (int)f0 * res + (int)f1;
    const float2* tab = tabs + (size_t)l * TSIZE;
    lo[l] = *reinterpret_cast<const float4*>(tab + base);
    hi[l] = *reinterpret_cast<const float4*>(tab + base + res);
  }
#pragma unroll
  for (int l = 0; l < 4; ++l) {
    const int res = RESV[12 + l];
    const float gs = (float)(2048.0 / (double)res);
    float f0 = floorf(xv.x / gs);
    float f1 = floorf(xv.y / gs);
    float g0 = f0 * gs;
    float g1 = f1 * gs;
    w0a[12 + l] = (xv.x - g0) / ((g0 + gs) - g0);
    w1a[12 + l] = (xv.y - g1) / ((g1 + gs) - g1);
    uint32_t u0 = (uint32_t)(int)f0;
    uint32_t u1m = (uint32_t)(int)f1 * P1U;
    const float2* tab = tabs + (size_t)(12 + l) * TSIZE;
    eh[l][0] = tab[(u0 ^ u1m) & MASKU];
    eh[l][1] = tab[(u0 ^ (u1m + P1U)) & MASKU];
    eh[l][2] = tab[((u0 + 1u) ^ u1m) & MASKU];
    eh[l][3] = tab[((u0 + 1u) ^ (u1m + P1U)) & MASKU];
  }

  float feat[32];
#pragma unroll
  for (int l = 0; l < 12; ++l) {
    float w0 = w0a[l], w1 = w1a[l];
    float omw0 = 1.0f - w0, omw1 = 1.0f - w1;
    float c0x = lo[l].x * omw1 + lo[l].z * w1;
    float c0y = lo[l].y * omw1 + lo[l].w * w1;
    float c1x = hi[l].x * omw1 + hi[l].z * w1;
    float c1y = hi[l].y * omw1 + hi[l].w * w1;
    feat[2 * l]     = c0x * omw0 + c1x * w0;
    feat[2 * l + 1] = c0y * omw0 + c1y * w0;
  }
#pragma unroll
  for (int l = 0; l < 4; ++l) {
    float w0 = w0a[12 + l], w1 = w1a[12 + l];
    float omw0 = 1.0f - w0, omw1 = 1.0f - w1;
    float c0x = eh[l][0].x * omw1 + eh[l][1].x * w1;
    float c0y = eh[l][0].y * omw1 + eh[l][1].y * w1;
    float c1x = eh[l][2].x * omw1 + eh[l][3].x * w1;
    float c1y = eh[l][2].y * omw1 + eh[l][3].y * w1;
    feat[24 + 2 * l]     = c0x * omw0 + c1x * w0;
    feat[24 + 2 * l + 1] = c0y * omw0 + c1y * w0;
  }

  float4* o = reinterpret_cast<float4*>(out) + (size_t)orig * 8;
#pragma unroll
  for (int j = 0; j < 8; ++j) {
    o[j] = make_float4(feat[4 * j], feat[4 * j + 1], feat[4 * j + 2], feat[4 * j + 3]);
  }
}

// ---------------- per-XCD partitioned capacity-bin sort ---------------------

// child index: 4 children of each 32-px parent are contiguous
__device__ __forceinline__ int child_of(float2 xv) {
  int bx = min((int)(xv.x * 0.0625f), CBINS_X - 1);   // 16-px coords
  int by = min((int)(xv.y * 0.0625f), CBINS_X - 1);
  int parent = ((bx >> 1) << 6) + (by >> 1);          // 64x64 parents
  int quad = ((bx & 1) << 1) + (by & 1);
  return (parent << 2) + quad;
}

__global__ __launch_bounds__(256) void scatter_px(
    const float2* __restrict__ xs, int* __restrict__ cnt,
    float4* __restrict__ recs,
    int* __restrict__ ovf, int* __restrict__ ovf_cnt, int B) {
  int p = blockIdx.x * 256 + threadIdx.x;
  if (p >= B) return;
  int part = blockIdx.x & 7;              // this block's XCD (round-robin map)
  float2 xv = xs[p];
  int pc = part * NCHILD + child_of(xv);  // (xcd, child) composite
  int pos = atomicAdd(&cnt[pc], 1);       // counter line local to this XCD
  if (pos < CAPX) {
    recs[(size_t)pc * CAPX + pos] =       // record line local to this XCD
        make_float4(xv.x, xv.y, __int_as_float(p), 0.0f);
  } else {
    int o = atomicAdd(ovf_cnt, 1);
    ovf[o] = p;  // ovf capacity == B: can never overflow
  }
}

__global__ __launch_bounds__(256, 2) void hashenc_px(
    const float4* __restrict__ recs, const int* __restrict__ cnt,
    const float* __restrict__ tables, float* __restrict__ out) {
  int bid = blockIdx.x;
  int nb = gridDim.x;                     // 16384, divisible by 8
  int chunk = nb >> 3;                    // 2048 = one partition's blocks
  bid = (bid & 7) * chunk + (bid >> 3);   // XCD k processes partition k
  int slot = bid * 256 + threadIdx.x;
  int pc = slot >> 5;                     // CAPX = 32 (pow2)
  int pos = slot & 31;
  int c = cnt[pc];
  if (pos >= min(c, CAPX)) return;        // empty slots: no recs read
  float4 r = recs[slot];                  // slot-coalesced 16B read
  embed_point(make_float2(r.x, r.y), __float_as_int(r.z), tables, out);
}

__global__ __launch_bounds__(256) void ovf_kernel(
    const float2* __restrict__ xs, const int* __restrict__ ovf,
    const int* __restrict__ ovf_cnt, const float* __restrict__ tables,
    float* __restrict__ out) {
  int n = *ovf_cnt;
  for (int i = blockIdx.x * 256 + threadIdx.x; i < n; i += gridDim.x * 256) {
    int p = ovf[i];
    embed_point(xs[p], p, tables, out);
  }
}

// ---------------- unsorted fallback -----------------------------------------

__global__ __launch_bounds__(256, 2) void hashenc_plain(
    const float2* __restrict__ xs, const float* __restrict__ tables,
    float* __restrict__ out, int B) {
  int p = blockIdx.x * 256 + threadIdx.x;
  if (p >= B) return;
  embed_point(xs[p], p, tables, out);
}

// ---------------- launch ----------------------------------------------------

extern "C" void kernel_launch(void* const* d_in, const int* in_sizes, int n_in,
                              void* d_out, int out_size, void* d_ws, size_t ws_size,
                              hipStream_t stream) {
  const float2* xs = (const float2*)d_in[0];
  const float* tables = (const float*)d_in[1];
  float* out = (float*)d_out;
  int B = in_sizes[0] / 2;
  int blocks = (B + 255) / 256;
  char* ws = (char*)d_ws;

  // layout: recs (16B*SLOTS = 67MB) | ovf (4B*B) | cnt (4B*8*NCHILD = 512KB)
  //         | ovf_cnt (+pad).  ws = 1 GiB (observed r14) -> fits.
  size_t c_recs = 0;
  size_t c_ovf = c_recs + (size_t)SLOTS * 16;
  size_t c_cnt = c_ovf + (size_t)B * 4;
  size_t c_ocnt = c_cnt + (size_t)XPART * NCHILD * 4;
  size_t need = c_ocnt + 64;

  bool grid_ok = (blocks & 7) == 0;
  if (grid_ok && ws_size >= need) {
    float4* recs = (float4*)(ws + c_recs);
    int* ovf = (int*)(ws + c_ovf);
    int* cnt = (int*)(ws + c_cnt);
    int* ovf_cnt = (int*)(ws + c_ocnt);
    (void)hipMemsetAsync(cnt, 0, (size_t)XPART * NCHILD * 4 + 64, stream);
    hipLaunchKernelGGL(scatter_px, dim3(blocks), dim3(256), 0, stream,
                       xs, cnt, recs, ovf, ovf_cnt, B);
    hipLaunchKernelGGL(hashenc_px, dim3(SLOTS / 256), dim3(256), 0, stream,
                       recs, cnt, tables, out);
    hipLaunchKernelGGL(ovf_kernel, dim3(32), dim3(256), 0, stream,
                       xs, ovf, ovf_cnt, tables, out);
  } else {
    hipLaunchKernelGGL(hashenc_plain, dim3(blocks), dim3(256), 0, stream,
                       xs, tables, out, B);
  }
}

// Round 16
// 277.527 us; speedup vs baseline: 2.3282x; 1.1027x over previous
//
#include <hip/hip_runtime.h>
#include <cstdint>

#define TSIZE (1u << 19)
#define MASKU (TSIZE - 1u)
#define P1U 2654435761u

// r16: per-XCD partitioned scatter (r15, proven fast) + child-compacted main.
//  - scatter: each block writes only partition blockIdx&7 -> record/counter
//    lines XCD-private -> no cross-XCD dirty-line bounce.
//  - main: block = one spatial child; gathers that child's points from ALL 8
//    partitions (prefix-sum + dense lane assignment) -> each table line
//    fetched by ONE XCD slab again (r15 regression: 8x table fetch), holes
//    compacted so trailing waves exit wave-uniformly.
//  - records AoS float4 (r11 A/B); NO nontemporal (r13); ws = 1 GiB (r14).
#define CBINS_X 128
#define NCHILD (CBINS_X * CBINS_X)      // 16384 children (16-px bins)
#define XPART 8
#define CAPX 32
#define SLOTS (XPART * NCHILD * CAPX)   // 4,194,304 slots (67 MB recs)

// ---------------- embed core (numerics FROZEN since round 2) ----------------
// RES[15] = 2047 (verified round 2). Levels 0-11 direct (fused 16B pair
// gathers); 12-15 hash; reference searchsorted == identity lookup.
// MLP structure: all 40 gathers issued before any lerp.
__device__ __forceinline__ void embed_point(float2 xv, int orig,
                                            const float* __restrict__ tables,
                                            float* __restrict__ out) {
  constexpr int RESV[16] = {16, 22, 30, 42, 58, 80, 111, 153,
                            212, 294, 406, 561, 776, 1072, 1482, 2047};
  const float2* tabs = reinterpret_cast<const float2*>(tables);

  float4 lo[12], hi[12];
  float2 eh[4][4];
  float w0a[16], w1a[16];

#pragma unroll
  for (int l = 0; l < 12; ++l) {
    const int res = RESV[l];
    const float gs = (float)(2048.0 / (double)res);  // f32(double(2048/res))
    float f0 = floorf(xv.x / gs);
    float f1 = floorf(xv.y / gs);
    float g0 = f0 * gs;
    float g1 = f1 * gs;
    w0a[l] = (xv.x - g0) / ((g0 + gs) - g0);
    w1a[l] = (xv.y - g1) / ((g1 + gs) - g1);
    int base = (int)f0 * res + (int)f1;
    const float2* tab = tabs + (size_t)l * TSIZE;
    lo[l] = *reinterpret_cast<const float4*>(tab + base);
    hi[l] = *reinterpret_cast<const float4*>(tab + base + res);
  }
#pragma unroll
  for (int l = 0; l < 4; ++l) {
    const int res = RESV[12 + l];
    const float gs = (float)(2048.0 / (double)res);
    float f0 = floorf(xv.x / gs);
    float f1 = floorf(xv.y / gs);
    float g0 = f0 * gs;
    float g1 = f1 * gs;
    w0a[12 + l] = (xv.x - g0) / ((g0 + gs) - g0);
    w1a[12 + l] = (xv.y - g1) / ((g1 + gs) - g1);
    uint32_t u0 = (uint32_t)(int)f0;
    uint32_t u1m = (uint32_t)(int)f1 * P1U;
    const float2* tab = tabs + (size_t)(12 + l) * TSIZE;
    eh[l][0] = tab[(u0 ^ u1m) & MASKU];
    eh[l][1] = tab[(u0 ^ (u1m + P1U)) & MASKU];
    eh[l][2] = tab[((u0 + 1u) ^ u1m) & MASKU];
    eh[l][3] = tab[((u0 + 1u) ^ (u1m + P1U)) & MASKU];
  }

  float feat[32];
#pragma unroll
  for (int l = 0; l < 12; ++l) {
    float w0 = w0a[l], w1 = w1a[l];
    float omw0 = 1.0f - w0, omw1 = 1.0f - w1;
    float c0x = lo[l].x * omw1 + lo[l].z * w1;
    float c0y = lo[l].y * omw1 + lo[l].w * w1;
    float c1x = hi[l].x * omw1 + hi[l].z * w1;
    float c1y = hi[l].y * omw1 + hi[l].w * w1;
    feat[2 * l]     = c0x * omw0 + c1x * w0;
    feat[2 * l + 1] = c0y * omw0 + c1y * w0;
  }
#pragma unroll
  for (int l = 0; l < 4; ++l) {
    float w0 = w0a[12 + l], w1 = w1a[12 + l];
    float omw0 = 1.0f - w0, omw1 = 1.0f - w1;
    float c0x = eh[l][0].x * omw1 + eh[l][1].x * w1;
    float c0y = eh[l][0].y * omw1 + eh[l][1].y * w1;
    float c1x = eh[l][2].x * omw1 + eh[l][3].x * w1;
    float c1y = eh[l][2].y * omw1 + eh[l][3].y * w1;
    feat[24 + 2 * l]     = c0x * omw0 + c1x * w0;
    feat[24 + 2 * l + 1] = c0y * omw0 + c1y * w0;
  }

  float4* o = reinterpret_cast<float4*>(out) + (size_t)orig * 8;
#pragma unroll
  for (int j = 0; j < 8; ++j) {
    o[j] = make_float4(feat[4 * j], feat[4 * j + 1], feat[4 * j + 2], feat[4 * j + 3]);
  }
}

// ---------------- per-XCD partitioned capacity-bin sort ---------------------

// child index: 4 children of each 32-px parent are contiguous
__device__ __forceinline__ int child_of(float2 xv) {
  int bx = min((int)(xv.x * 0.0625f), CBINS_X - 1);   // 16-px coords
  int by = min((int)(xv.y * 0.0625f), CBINS_X - 1);
  int parent = ((bx >> 1) << 6) + (by >> 1);          // 64x64 parents
  int quad = ((bx & 1) << 1) + (by & 1);
  return (parent << 2) + quad;
}

__global__ __launch_bounds__(256) void scatter_px(
    const float2* __restrict__ xs, int* __restrict__ cnt,
    float4* __restrict__ recs,
    int* __restrict__ ovf, int* __restrict__ ovf_cnt, int B) {
  int p = blockIdx.x * 256 + threadIdx.x;
  if (p >= B) return;
  int part = blockIdx.x & 7;              // this block's XCD (round-robin map)
  float2 xv = xs[p];
  int pc = part * NCHILD + child_of(xv);  // (xcd, child) composite
  int pos = atomicAdd(&cnt[pc], 1);       // counter line local to this XCD
  if (pos < CAPX) {
    recs[(size_t)pc * CAPX + pos] =       // record line local to this XCD
        make_float4(xv.x, xv.y, __int_as_float(p), 0.0f);
  } else {
    int o = atomicAdd(ovf_cnt, 1);
    ovf[o] = p;  // ovf capacity == B: can never overflow
  }
}

// main: block = one child; compact dense lane assignment over 8 partitions
__global__ __launch_bounds__(256, 2) void hashenc_cmp(
    const float4* __restrict__ recs, const int* __restrict__ cnt,
    const float* __restrict__ tables, float* __restrict__ out) {
  __shared__ int pre[9];
  int bid = blockIdx.x;
  int nb = gridDim.x;                     // 16384, divisible by 8
  int chunk = nb >> 3;                    // 2048 children per XCD slab
  int child = (bid & 7) * chunk + (bid >> 3);   // XCD k owns slab k (spatial)
  if (threadIdx.x == 0) {
    int s = 0;
    pre[0] = 0;
#pragma unroll
    for (int k = 0; k < XPART; ++k) {
      s += min(cnt[k * NCHILD + child], CAPX);
      pre[k + 1] = s;
    }
  }
  __syncthreads();
  int total = pre[8];
  int i = threadIdx.x;
  if (i >= total) return;                 // trailing waves exit wave-uniformly
  int k = 0;
#pragma unroll
  for (int kk = 1; kk < XPART; ++kk) k = (i >= pre[kk]) ? kk : k;
  int j = i - pre[k];
  float4 r = recs[((size_t)(k * NCHILD + child)) * CAPX + j];
  embed_point(make_float2(r.x, r.y), __float_as_int(r.z), tables, out);
}

__global__ __launch_bounds__(256) void ovf_kernel(
    const float2* __restrict__ xs, const int* __restrict__ ovf,
    const int* __restrict__ ovf_cnt, const float* __restrict__ tables,
    float* __restrict__ out) {
  int n = *ovf_cnt;
  for (int i = blockIdx.x * 256 + threadIdx.x; i < n; i += gridDim.x * 256) {
    int p = ovf[i];
    embed_point(xs[p], p, tables, out);
  }
}

// ---------------- unsorted fallback -----------------------------------------

__global__ __launch_bounds__(256, 2) void hashenc_plain(
    const float2* __restrict__ xs, const float* __restrict__ tables,
    float* __restrict__ out, int B) {
  int p = blockIdx.x * 256 + threadIdx.x;
  if (p >= B) return;
  embed_point(xs[p], p, tables, out);
}

// ---------------- launch ----------------------------------------------------

extern "C" void kernel_launch(void* const* d_in, const int* in_sizes, int n_in,
                              void* d_out, int out_size, void* d_ws, size_t ws_size,
                              hipStream_t stream) {
  const float2* xs = (const float2*)d_in[0];
  const float* tables = (const float*)d_in[1];
  float* out = (float*)d_out;
  int B = in_sizes[0] / 2;
  int blocks = (B + 255) / 256;
  char* ws = (char*)d_ws;

  // layout: recs (16B*SLOTS = 67MB) | ovf (4B*B) | cnt (4B*8*NCHILD = 512KB)
  //         | ovf_cnt (+pad)
  size_t c_recs = 0;
  size_t c_ovf = c_recs + (size_t)SLOTS * 16;
  size_t c_cnt = c_ovf + (size_t)B * 4;
  size_t c_ocnt = c_cnt + (size_t)XPART * NCHILD * 4;
  size_t need = c_ocnt + 64;

  bool grid_ok = (blocks & 7) == 0;
  if (grid_ok && ws_size >= need) {
    float4* recs = (float4*)(ws + c_recs);
    int* ovf = (int*)(ws + c_ovf);
    int* cnt = (int*)(ws + c_cnt);
    int* ovf_cnt = (int*)(ws + c_ocnt);
    (void)hipMemsetAsync(cnt, 0, (size_t)XPART * NCHILD * 4 + 64, stream);
    hipLaunchKernelGGL(scatter_px, dim3(blocks), dim3(256), 0, stream,
                       xs, cnt, recs, ovf, ovf_cnt, B);
    hipLaunchKernelGGL(hashenc_cmp, dim3(NCHILD), dim3(256), 0, stream,
                       recs, cnt, tables, out);
    hipLaunchKernelGGL(ovf_kernel, dim3(32), dim3(256), 0, stream,
                       xs, ovf, ovf_cnt, tables, out);
  } else {
    hipLaunchKernelGGL(hashenc_plain, dim3(blocks), dim3(256), 0, stream,
                       xs, tables, out, B);
  }
}